// Round 9
// baseline (288.054 us; speedup 1.0000x reference)
//
#include <hip/hip_runtime.h>

// GraphGATNet 2-layer GAT. Round 9:
//  - agg: XCD-PINNED channel chunking. H stored as 4 separate arrays
//    [chunk][N][32ch] (no 128B-line sharing between chunks, unlike R6) and
//    chunk = (blockIdx%8)>>1 so each XCD pair only gathers from its own
//    3.2MB chunk array -> L2-resident (was: 12.8MB shared across 8 L2s,
//    108MB FETCH). R6 failed because chunks shared lines AND every XCD
//    processed every chunk; both fixed here.
//  - ring kept (6 uint slots, tiny VGPR), weights per chunk = its heads only.
//  - GEMMs write H chunked (index permutation). o1bf/out stay row-major.
//  - CSR build unchanged from R8.

constexpr int N_NODES = 50000;
constexpr int E_EDGES = 800000;
constexpr int ETOT = E_EDGES + N_NODES;
constexpr float NEG_SLOPE = 0.2f;
constexpr float EPS = 1e-16f;
constexpr int SCAN_BLK = 512;
constexpr int NBLK_SCAN = (N_NODES + SCAN_BLK - 1) / SCAN_BLK;   // 98
constexpr size_t NC32 = (size_t)N_NODES * 32;

typedef short bf16x8 __attribute__((ext_vector_type(8)));
typedef float f32x4 __attribute__((ext_vector_type(4)));

__device__ __forceinline__ float lrelu(float x) { return x > 0.f ? x : NEG_SLOPE * x; }
__device__ __forceinline__ ushort f2bf(float f) {
    uint u = __float_as_uint(f);
    return (ushort)((u + 0x7fffu + ((u >> 16) & 1u)) >> 16);
}
__device__ __forceinline__ float bf2f(uint u) { return __uint_as_float(u << 16); }

// ---------------- setup: W->bf16T, vs/vd = W2@att2, zero cnt16 ----------------
__global__ __launch_bounds__(256) void convert_W(const float* __restrict__ W1,
                                                 const float* __restrict__ W2,
                                                 const float* __restrict__ attS2,
                                                 const float* __restrict__ attD2,
                                                 ushort* __restrict__ W1t,
                                                 ushort* __restrict__ W2t,
                                                 float* __restrict__ vs,
                                                 float* __restrict__ vd,
                                                 uint* __restrict__ cnt16) {
    const int t = threadIdx.x;
    if (blockIdx.x >= 2) {
        const int i = (blockIdx.x - 2) * 256 + t;
        if (i < (N_NODES + 1) / 2) cnt16[i] = 0;
        return;
    }
    const float* W = (blockIdx.x == 0) ? W1 : W2;
    ushort* Wt = (blockIdx.x == 0) ? W1t : W2t;
    const int n = t >> 1, k0 = (t & 1) * 64;
    for (int k = 0; k < 64; k += 2) {
        uint lo = f2bf(W[(size_t)(k0 + k) * 128 + n]);
        uint hi = f2bf(W[(size_t)(k0 + k + 1) * 128 + n]);
        *(uint*)&Wt[(size_t)n * 128 + k0 + k] = lo | (hi << 16);
    }
    if (blockIdx.x == 1) {
        const int k = t & 127;
        const float* av = (t < 128) ? attS2 : attD2;
        float* dst = (t < 128) ? vs : vd;
        float s = 0.f;
        for (int c = 0; c < 128; ++c) s += W2[(size_t)k * 128 + c] * av[c];
        dst[k] = s;
    }
}

// count + rank in one pass (packed 2x16-bit counts)
__global__ __launch_bounds__(256) void count_rank(const int* __restrict__ ei,
                                                  uint* __restrict__ cnt16,
                                                  ushort* __restrict__ rank) {
    int e = blockIdx.x * blockDim.x + threadIdx.x;
    if (e >= ETOT) return;
    int d = (e < E_EDGES) ? ei[E_EDGES + e] : (e - E_EDGES);
    const uint shift = (d & 1) * 16;
    uint old = atomicAdd(&cnt16[d >> 1], 1u << shift);
    rank[e] = (ushort)((old >> shift) & 0xffffu);
}

__device__ __forceinline__ uint cnt_at(const uint* cnt16, int i) {
    return (cnt16[i >> 1] >> ((i & 1) * 16)) & 0xffffu;
}

__global__ __launch_bounds__(SCAN_BLK) void block_sums(const uint* __restrict__ cnt16,
                                                       int* __restrict__ bsum) {
    __shared__ int sm[SCAN_BLK];
    int i = blockIdx.x * SCAN_BLK + threadIdx.x;
    sm[threadIdx.x] = (i < N_NODES) ? (int)cnt_at(cnt16, i) : 0;
    __syncthreads();
    for (int off = SCAN_BLK / 2; off > 0; off >>= 1) {
        if (threadIdx.x < off) sm[threadIdx.x] += sm[threadIdx.x + off];
        __syncthreads();
    }
    if (threadIdx.x == 0) bsum[blockIdx.x] = sm[0];
}

__global__ __launch_bounds__(SCAN_BLK) void scan_final_fused(const uint* __restrict__ cnt16,
                                                             const int* __restrict__ bsum,
                                                             int* __restrict__ rowptr) {
    __shared__ int sb[128];
    __shared__ int sm[SCAN_BLK];
    const int t = threadIdx.x;
    if (t < 128) sb[t] = (t < NBLK_SCAN) ? bsum[t] : 0;
    __syncthreads();
    for (int off = 1; off < 128; off <<= 1) {
        int v = 0;
        if (t < 128 && t >= off) v = sb[t - off];
        __syncthreads();
        if (t < 128) sb[t] += v;
        __syncthreads();
    }
    const int bid = blockIdx.x;
    const int bpre = sb[bid] - bsum[bid];

    const int i = bid * SCAN_BLK + t;
    const int v = (i < N_NODES) ? (int)cnt_at(cnt16, i) : 0;
    sm[t] = v;
    __syncthreads();
    for (int off = 1; off < SCAN_BLK; off <<= 1) {
        int x = (t >= off) ? sm[t - off] : 0;
        __syncthreads();
        sm[t] += x;
        __syncthreads();
    }
    if (i < N_NODES) rowptr[i] = bpre + sm[t] - v;
    if (bid == 0 && t == 0) rowptr[N_NODES] = ETOT;
}

__global__ __launch_bounds__(256) void scatter_kernel(const int* __restrict__ ei,
                                                      const int* __restrict__ rowptr,
                                                      const ushort* __restrict__ rank,
                                                      int* __restrict__ csrc) {
    int e = blockIdx.x * blockDim.x + threadIdx.x;
    if (e >= ETOT) return;
    int s, d;
    if (e < E_EDGES) { s = ei[e]; d = ei[E_EDGES + e]; }
    else             { s = d = e - E_EDGES; }
    const int pos = rowptr[d] + (int)rank[e];
    __builtin_nontemporal_store(s, &csrc[pos]);
}

// ---------------- MFMA GEMM: H(bf16, CHUNKED [4][N][32]) = X @ W ----------------
template <bool BF16IN, bool ATT8, bool ATTIN>
__global__ __launch_bounds__(256) void mfma_gemm(const void* __restrict__ Xv,
                                                 const ushort* __restrict__ Wt,
                                                 ushort* __restrict__ H,
                                                 const float* __restrict__ attS,
                                                 const float* __restrict__ attD,
                                                 float* __restrict__ aS,
                                                 float* __restrict__ aD,
                                                 int nrows) {
    __shared__ __align__(16) char smem[16384 + 32768];
    ushort* lx = (ushort*)smem;            // 64 x 128 bf16 (swizzled)
    ushort* lw = (ushort*)(smem + 16384);  // 128 x 128 bf16 (swizzled)
    float*  hs = (float*)smem;             // ATT8 epilogue alias: 64 x 130 f32

    const int t = threadIdx.x;
    const int r0 = blockIdx.x * 64;

    // stage W
    {
        const int n = t >> 1, half = t & 1;
        const ushort* src = Wt + (size_t)n * 128 + half * 64;
        #pragma unroll
        for (int c = 0; c < 8; ++c) {
            int cx = half * 8 + c;
            uint4 v = *(const uint4*)(src + c * 8);
            *(uint4*)&lw[(n * 16 + (cx ^ (n & 7))) * 8] = v;
        }
    }
    // stage X
    {
        const int r = t >> 2, q = t & 3;
        const int grow = r0 + r;
        const uint4 z = {0, 0, 0, 0};
        #pragma unroll
        for (int cc = 0; cc < 4; ++cc) {
            int cx = q * 4 + cc;
            uint4 packed = z;
            if (grow < nrows) {
                if (BF16IN) {
                    packed = *(const uint4*)((const ushort*)Xv + (size_t)grow * 128 + cx * 8);
                } else {
                    const float* X = (const float*)Xv;
                    const float4 f0 = *(const float4*)(X + (size_t)grow * 128 + cx * 8);
                    const float4 f1 = *(const float4*)(X + (size_t)grow * 128 + cx * 8 + 4);
                    packed.x = (uint)f2bf(f0.x) | ((uint)f2bf(f0.y) << 16);
                    packed.y = (uint)f2bf(f0.z) | ((uint)f2bf(f0.w) << 16);
                    packed.z = (uint)f2bf(f1.x) | ((uint)f2bf(f1.y) << 16);
                    packed.w = (uint)f2bf(f1.z) | ((uint)f2bf(f1.w) << 16);
                }
            }
            *(uint4*)&lx[(r * 16 + (cx ^ (r & 7))) * 8] = packed;
        }
    }
    __syncthreads();

    const int wv = t >> 6, l = t & 63;
    const int row = wv * 16 + (l & 15);
    const int lg = l >> 4;
    f32x4 acc[8] = {};

    #pragma unroll
    for (int kb = 0; kb < 4; ++kb) {
        const int cx = kb * 4 + lg;
        bf16x8 a = *(const bf16x8*)&lx[(row * 16 + (cx ^ (row & 7))) * 8];
        #pragma unroll
        for (int nt = 0; nt < 8; ++nt) {
            const int n = nt * 16 + (l & 15);
            bf16x8 b = *(const bf16x8*)&lw[(n * 16 + (cx ^ (n & 7))) * 8];
            acc[nt] = __builtin_amdgcn_mfma_f32_16x16x32_bf16(a, b, acc[nt], 0, 0, 0);
        }
    }

    // C/D layout: col = lane&15, row = (lane>>4)*4 + reg. Chunked H write:
    // channel = nt*16 + (l&15) -> chunk = nt>>1, within = (nt&1)*16 + (l&15)
    #pragma unroll
    for (int reg = 0; reg < 4; ++reg) {
        const int grow = r0 + wv * 16 + lg * 4 + reg;
        if (grow < nrows) {
            #pragma unroll
            for (int nt = 0; nt < 8; ++nt)
                H[(size_t)(nt >> 1) * NC32 + (size_t)grow * 32 + (nt & 1) * 16 + (l & 15)] =
                    f2bf(acc[nt][reg]);
        }
    }

    if (ATT8) {
        __syncthreads();   // all MFMA LDS reads done; safe to overwrite as hs
        #pragma unroll
        for (int reg = 0; reg < 4; ++reg) {
            const int r = wv * 16 + lg * 4 + reg;
            #pragma unroll
            for (int nt = 0; nt < 8; ++nt)
                hs[r * 130 + nt * 16 + (l & 15)] = acc[nt][reg];
        }
        __syncthreads();
        for (int q = t; q < 512; q += 256) {
            const int r = q >> 3, h = q & 7;
            if (r0 + r < nrows) {
                float sv = 0.f, dv = 0.f;
                #pragma unroll
                for (int j = 0; j < 16; ++j) {
                    const float hv = hs[r * 130 + h * 16 + j];
                    sv += hv * attS[h * 16 + j];
                    dv += hv * attD[h * 16 + j];
                }
                aS[(size_t)(r0 + r) * 8 + h] = sv;
                aD[(size_t)(r0 + r) * 8 + h] = dv;
            }
        }
    }

    if (ATTIN) {
        // lx still holds staged input rows. attS/attD = vs/vd; aS/aD = aS2/aD2.
        const int r = t >> 2, qq = t & 3;
        float ps = 0.f, pd = 0.f;
        #pragma unroll
        for (int cc = 0; cc < 4; ++cc) {
            const int cx = qq * 4 + cc;
            const uint4 p = *(const uint4*)&lx[(r * 16 + (cx ^ (r & 7))) * 8];
            const uint w[4] = {p.x, p.y, p.z, p.w};
            #pragma unroll
            for (int q = 0; q < 4; ++q) {
                const float e0 = bf2f(w[q] & 0xffffu);
                const float e1 = bf2f(w[q] >> 16);
                ps += e0 * attS[cx * 8 + 2 * q] + e1 * attS[cx * 8 + 2 * q + 1];
                pd += e0 * attD[cx * 8 + 2 * q] + e1 * attD[cx * 8 + 2 * q + 1];
            }
        }
        ps += __shfl_xor(ps, 1); ps += __shfl_xor(ps, 2);
        pd += __shfl_xor(pd, 1); pd += __shfl_xor(pd, 2);
        if (qq == 0 && r0 + r < nrows) { aS[r0 + r] = ps; aD[r0 + r] = pd; }
    }
}

// ---------------- agg, XCD-pinned channel chunks ----------------
// chunk = (blockIdx%8)>>1  (two XCDs per 32-channel chunk; 3.2MB L2-resident)
// local dst-quad = (blockIdx>>3)*2 + (blockIdx&1)   (bijective over 12500)
// lane = 16g+i: group g handles edges j = 4t+g; lane i covers 2 channels.
#define GISSUE32(P, JJ)                                                        \
    {                                                                          \
        const int jx_ = (JJ);                                                  \
        const int sx_ = __shfl(s_l, jx_ & 63);                                 \
        P = 0u;                                                                \
        if (jx_ < rem) P = *(const uint*)(Hm + (size_t)sx_ * 32 + i * 2);      \
    }

__global__ __launch_bounds__(256) void agg8x(const int* __restrict__ rowptr,
                                             const int* __restrict__ csrc,
                                             const float* __restrict__ aS,
                                             const float* __restrict__ aD,
                                             const ushort* __restrict__ Hc,
                                             const float* __restrict__ bias,
                                             ushort* __restrict__ o1bf) {
    __shared__ float wlds[4][128];
    const int b = blockIdx.x;
    const int c = (b & 7) >> 1;
    const int local = ((b >> 3) << 1) | (b & 1);
    const int wv = threadIdx.x >> 6;
    const int d = local * 4 + wv;
    const int lane = threadIdx.x & 63;
    const int g = lane >> 4, i = lane & 15;
    const int hc = i >> 3;                      // which of my chunk's 2 heads
    const int h0 = 2 * c;
    const ushort* Hm = Hc + (size_t)c * NC32;

    const float ad0 = aD[(size_t)d * 8 + h0];
    const float ad1 = aD[(size_t)d * 8 + h0 + 1];

    const int base = rowptr[d], end = rowptr[d + 1];
    float a0 = 0.f, a1 = 0.f, ws = 0.f;

    for (int c0 = base; c0 < end; c0 += 64) {
        const int rem = min(64, end - c0);
        const int s_l = (lane < rem) ? csrc[c0 + lane] : 0;

        uint ring[6];
        #pragma unroll
        for (int s = 0; s < 6; ++s) GISSUE32(ring[s], 4 * s + g);

        // weights for this chunk's 2 heads: lane computes edge = lane
        float w0 = 0.f, w1 = 0.f;
        if (lane < rem) {
            const float2 as2 = *(const float2*)&aS[(size_t)s_l * 8 + h0];
            w0 = __expf(lrelu(as2.x + ad0));
            w1 = __expf(lrelu(as2.y + ad1));
        }
        wlds[wv][lane * 2 + 0] = w0;
        wlds[wv][lane * 2 + 1] = w1;
        // wave-private LDS, lockstep => no barrier

        const int niter = (rem + 3) >> 2;
        for (int tb = 0; tb < niter; tb += 6) {
            #pragma unroll
            for (int s = 0; s < 6; ++s) {
                if (tb + s < niter) {
                    const int j = (tb + s) * 4 + g;
                    const float w = (j < rem) ? wlds[wv][j * 2 + hc] : 0.f;
                    const uint p = ring[s];
                    a0 += w * bf2f(p & 0xffffu);
                    a1 += w * bf2f(p >> 16);
                    ws += w;
                    GISSUE32(ring[s], j + 24);
                }
            }
        }
    }

    a0 += __shfl_xor(a0, 16); a0 += __shfl_xor(a0, 32);
    a1 += __shfl_xor(a1, 16); a1 += __shfl_xor(a1, 32);
    ws += __shfl_xor(ws, 16); ws += __shfl_xor(ws, 32);

    if (g == 0) {
        const float inv = 1.f / (ws + EPS);   // ws = per-head denom (head hc)
        const int ch = c * 32 + i * 2;
        const float v0 = fmaxf(a0 * inv + bias[ch + 0], 0.f);
        const float v1 = fmaxf(a1 * inv + bias[ch + 1], 0.f);
        *(uint*)(o1bf + (size_t)d * 128 + ch) = (uint)f2bf(v0) | ((uint)f2bf(v1) << 16);
    }
}

__global__ __launch_bounds__(256) void agg1x(const int* __restrict__ rowptr,
                                             const int* __restrict__ csrc,
                                             const float* __restrict__ aS,
                                             const float* __restrict__ aD,
                                             const ushort* __restrict__ Hc,
                                             const float* __restrict__ bias,
                                             float* __restrict__ out) {
    __shared__ float wlds[4][64];
    const int b = blockIdx.x;
    const int c = (b & 7) >> 1;
    const int local = ((b >> 3) << 1) | (b & 1);
    const int wv = threadIdx.x >> 6;
    const int d = local * 4 + wv;
    const int lane = threadIdx.x & 63;
    const int g = lane >> 4, i = lane & 15;
    const ushort* Hm = Hc + (size_t)c * NC32;
    const float ad = aD[d];

    const int base = rowptr[d], end = rowptr[d + 1];
    float a0 = 0.f, a1 = 0.f, ws = 0.f;

    for (int c0 = base; c0 < end; c0 += 64) {
        const int rem = min(64, end - c0);
        const int s_l = (lane < rem) ? csrc[c0 + lane] : 0;

        uint ring[6];
        #pragma unroll
        for (int s = 0; s < 6; ++s) GISSUE32(ring[s], 4 * s + g);

        wlds[wv][lane] = (lane < rem) ? __expf(lrelu(aS[s_l] + ad)) : 0.f;

        const int niter = (rem + 3) >> 2;
        for (int tb = 0; tb < niter; tb += 6) {
            #pragma unroll
            for (int s = 0; s < 6; ++s) {
                if (tb + s < niter) {
                    const int j = (tb + s) * 4 + g;
                    const float w = (j < rem) ? wlds[wv][j] : 0.f;
                    const uint p = ring[s];
                    a0 += w * bf2f(p & 0xffffu);
                    a1 += w * bf2f(p >> 16);
                    ws += w;
                    GISSUE32(ring[s], j + 24);
                }
            }
        }
    }

    a0 += __shfl_xor(a0, 16); a0 += __shfl_xor(a0, 32);
    a1 += __shfl_xor(a1, 16); a1 += __shfl_xor(a1, 32);
    ws += __shfl_xor(ws, 16); ws += __shfl_xor(ws, 32);

    if (g == 0) {
        const float inv = 1.f / (ws + EPS);
        const int ch = c * 32 + i * 2;
        float2 o;
        o.x = a0 * inv + bias[ch + 0];
        o.y = a1 * inv + bias[ch + 1];
        *(float2*)(out + (size_t)d * 128 + ch) = o;
    }
}

extern "C" void kernel_launch(void* const* d_in, const int* in_sizes, int n_in,
                              void* d_out, int out_size, void* d_ws, size_t ws_size,
                              hipStream_t stream) {
    const float* x        = (const float*)d_in[0];
    const int*   ei       = (const int*)  d_in[1];
    const float* W1       = (const float*)d_in[2];
    const float* att_src1 = (const float*)d_in[3];
    const float* att_dst1 = (const float*)d_in[4];
    const float* b1       = (const float*)d_in[5];
    const float* W2       = (const float*)d_in[6];
    const float* att_src2 = (const float*)d_in[7];
    const float* att_dst2 = (const float*)d_in[8];
    const float* b2       = (const float*)d_in[9];
    float* out = (float*)d_out;

    // Workspace layout
    ushort* Hbf  = (ushort*)d_ws;                          // [4][N][32] bf16 (h1, then h2)
    ushort* o1bf = Hbf + (size_t)N_NODES * 128;            // N*128 bf16 row-major
    float*  aS1  = (float*)(o1bf + (size_t)N_NODES * 128); // N*8
    float*  aD1  = aS1 + (size_t)N_NODES * 8;              // N*8
    float*  aS2  = aD1 + (size_t)N_NODES * 8;              // N
    float*  aD2  = aS2 + N_NODES;                          // N
    float*  vs   = aD2 + N_NODES;                          // 128
    float*  vd   = vs + 128;                               // 128
    ushort* W1t  = (ushort*)(vd + 128);                    // 128*128
    ushort* W2t  = W1t + 128 * 128;                        // 128*128
    uint* cnt16  = (uint*)(W2t + 128 * 128);               // (N+1)/2 words
    int* rowptr  = (int*)(cnt16 + (N_NODES + 1) / 2 + 1);  // N+1
    int* bsum    = rowptr + N_NODES + 1;                   // 128
    ushort* rank = (ushort*)(bsum + 128);                  // ETOT
    int* csrc    = (int*)(rank + ETOT + 2);                // ETOT

    const int zblk = ((N_NODES + 1) / 2 + 255) / 256;      // 98
    const int eblk = (ETOT + 255) / 256;                   // 3321
    const int gemm_blocks = (N_NODES + 63) / 64;           // 782
    const int agg_blocks = 50000;                          // 4 chunks x 12500

    convert_W<<<2 + zblk, 256, 0, stream>>>(W1, W2, att_src2, att_dst2,
                                            W1t, W2t, vs, vd, cnt16);
    count_rank<<<eblk, 256, 0, stream>>>(ei, cnt16, rank);
    block_sums<<<NBLK_SCAN, SCAN_BLK, 0, stream>>>(cnt16, bsum);
    scan_final_fused<<<NBLK_SCAN, SCAN_BLK, 0, stream>>>(cnt16, bsum, rowptr);
    scatter_kernel<<<eblk, 256, 0, stream>>>(ei, rowptr, rank, csrc);

    // Layer 1
    mfma_gemm<false, true, false><<<gemm_blocks, 256, 0, stream>>>(
        x, W1t, Hbf, att_src1, att_dst1, aS1, aD1, N_NODES);
    agg8x<<<agg_blocks, 256, 0, stream>>>(rowptr, csrc, aS1, aD1, Hbf, b1, o1bf);

    // Layer 2 (GEMM2 also computes a2 dots from its staged input rows)
    mfma_gemm<true, false, true><<<gemm_blocks, 256, 0, stream>>>(
        o1bf, W2t, Hbf, vs, vd, aS2, aD2, N_NODES);
    agg1x<<<agg_blocks, 256, 0, stream>>>(rowptr, csrc, aS2, aD2, Hbf, b2, out);
}

// Round 10
// 217.420 us; speedup vs baseline: 1.3249x; 1.3249x over previous
//
#include <hip/hip_runtime.h>

// GraphGATNet 2-layer GAT. Round 10:
//  - REVERT R9 XCD-chunking (2nd chunking failure: FETCH unchanged 103MB ->
//    L2 pinning doesn't materialize; per-edge VALU 4x -> 86% VALUBusy, 95us).
//  - agg = R5 structure (best: 48us): 4-slot uint4 ring, 16 lanes/edge.
//    NEW: lean unpack (u<<16 / u&0xffff0000, 2 ops/uint) + float2 accumulators
//    (__builtin_elementwise_fma -> v_pk_fma_f32) to cut inner VALU ~35%.
//  - csrc stored as ushort (N<2^16): halves scatter writes + agg csrc reads.
//  - CSR build, MFMA GEMMs with fused att dots unchanged from R8.

constexpr int N_NODES = 50000;
constexpr int E_EDGES = 800000;
constexpr int ETOT = E_EDGES + N_NODES;
constexpr float NEG_SLOPE = 0.2f;
constexpr float EPS = 1e-16f;
constexpr int SCAN_BLK = 512;
constexpr int NBLK_SCAN = (N_NODES + SCAN_BLK - 1) / SCAN_BLK;   // 98

typedef short bf16x8 __attribute__((ext_vector_type(8)));
typedef float f32x4 __attribute__((ext_vector_type(4)));
typedef float f32x2 __attribute__((ext_vector_type(2)));

__device__ __forceinline__ float lrelu(float x) { return x > 0.f ? x : NEG_SLOPE * x; }
__device__ __forceinline__ ushort f2bf(float f) {
    uint u = __float_as_uint(f);
    return (ushort)((u + 0x7fffu + ((u >> 16) & 1u)) >> 16);
}
__device__ __forceinline__ float bf2f(uint u) { return __uint_as_float(u << 16); }

// lean: 2 VALU unpack + 1 v_pk_fma_f32 per bf16-pair
__device__ __forceinline__ void fma_pair(f32x2& acc, uint u, f32x2 w2) {
    f32x2 h;
    h.x = __uint_as_float(u << 16);
    h.y = __uint_as_float(u & 0xffff0000u);
    acc = __builtin_elementwise_fma(h, w2, acc);
}

__device__ __forceinline__ void fma8v(f32x2* acc, uint4 p, float w, float& ws) {
    ws += w;
    const f32x2 w2 = {w, w};
    fma_pair(acc[0], p.x, w2);
    fma_pair(acc[1], p.y, w2);
    fma_pair(acc[2], p.z, w2);
    fma_pair(acc[3], p.w, w2);
}

// ---------------- setup: W->bf16T, vs/vd = W2@att2, zero cnt16 ----------------
__global__ __launch_bounds__(256) void convert_W(const float* __restrict__ W1,
                                                 const float* __restrict__ W2,
                                                 const float* __restrict__ attS2,
                                                 const float* __restrict__ attD2,
                                                 ushort* __restrict__ W1t,
                                                 ushort* __restrict__ W2t,
                                                 float* __restrict__ vs,
                                                 float* __restrict__ vd,
                                                 uint* __restrict__ cnt16) {
    const int t = threadIdx.x;
    if (blockIdx.x >= 2) {
        const int i = (blockIdx.x - 2) * 256 + t;
        if (i < (N_NODES + 1) / 2) cnt16[i] = 0;
        return;
    }
    const float* W = (blockIdx.x == 0) ? W1 : W2;
    ushort* Wt = (blockIdx.x == 0) ? W1t : W2t;
    const int n = t >> 1, k0 = (t & 1) * 64;
    for (int k = 0; k < 64; k += 2) {
        uint lo = f2bf(W[(size_t)(k0 + k) * 128 + n]);
        uint hi = f2bf(W[(size_t)(k0 + k + 1) * 128 + n]);
        *(uint*)&Wt[(size_t)n * 128 + k0 + k] = lo | (hi << 16);
    }
    if (blockIdx.x == 1) {
        const int k = t & 127;
        const float* av = (t < 128) ? attS2 : attD2;
        float* dst = (t < 128) ? vs : vd;
        float s = 0.f;
        for (int c = 0; c < 128; ++c) s += W2[(size_t)k * 128 + c] * av[c];
        dst[k] = s;
    }
}

// count + rank in one pass (packed 2x16-bit counts)
__global__ __launch_bounds__(256) void count_rank(const int* __restrict__ ei,
                                                  uint* __restrict__ cnt16,
                                                  ushort* __restrict__ rank) {
    int e = blockIdx.x * blockDim.x + threadIdx.x;
    if (e >= ETOT) return;
    int d = (e < E_EDGES) ? ei[E_EDGES + e] : (e - E_EDGES);
    const uint shift = (d & 1) * 16;
    uint old = atomicAdd(&cnt16[d >> 1], 1u << shift);
    rank[e] = (ushort)((old >> shift) & 0xffffu);
}

__device__ __forceinline__ uint cnt_at(const uint* cnt16, int i) {
    return (cnt16[i >> 1] >> ((i & 1) * 16)) & 0xffffu;
}

__global__ __launch_bounds__(SCAN_BLK) void block_sums(const uint* __restrict__ cnt16,
                                                       int* __restrict__ bsum) {
    __shared__ int sm[SCAN_BLK];
    int i = blockIdx.x * SCAN_BLK + threadIdx.x;
    sm[threadIdx.x] = (i < N_NODES) ? (int)cnt_at(cnt16, i) : 0;
    __syncthreads();
    for (int off = SCAN_BLK / 2; off > 0; off >>= 1) {
        if (threadIdx.x < off) sm[threadIdx.x] += sm[threadIdx.x + off];
        __syncthreads();
    }
    if (threadIdx.x == 0) bsum[blockIdx.x] = sm[0];
}

__global__ __launch_bounds__(SCAN_BLK) void scan_final_fused(const uint* __restrict__ cnt16,
                                                             const int* __restrict__ bsum,
                                                             int* __restrict__ rowptr) {
    __shared__ int sb[128];
    __shared__ int sm[SCAN_BLK];
    const int t = threadIdx.x;
    if (t < 128) sb[t] = (t < NBLK_SCAN) ? bsum[t] : 0;
    __syncthreads();
    for (int off = 1; off < 128; off <<= 1) {
        int v = 0;
        if (t < 128 && t >= off) v = sb[t - off];
        __syncthreads();
        if (t < 128) sb[t] += v;
        __syncthreads();
    }
    const int bid = blockIdx.x;
    const int bpre = sb[bid] - bsum[bid];

    const int i = bid * SCAN_BLK + t;
    const int v = (i < N_NODES) ? (int)cnt_at(cnt16, i) : 0;
    sm[t] = v;
    __syncthreads();
    for (int off = 1; off < SCAN_BLK; off <<= 1) {
        int x = (t >= off) ? sm[t - off] : 0;
        __syncthreads();
        sm[t] += x;
        __syncthreads();
    }
    if (i < N_NODES) rowptr[i] = bpre + sm[t] - v;
    if (bid == 0 && t == 0) rowptr[N_NODES] = ETOT;
}

__global__ __launch_bounds__(256) void scatter_kernel(const int* __restrict__ ei,
                                                      const int* __restrict__ rowptr,
                                                      const ushort* __restrict__ rank,
                                                      ushort* __restrict__ csrc) {
    int e = blockIdx.x * blockDim.x + threadIdx.x;
    if (e >= ETOT) return;
    int s, d;
    if (e < E_EDGES) { s = ei[e]; d = ei[E_EDGES + e]; }
    else             { s = d = e - E_EDGES; }
    const int pos = rowptr[d] + (int)rank[e];
    __builtin_nontemporal_store((ushort)s, &csrc[pos]);
}

// ---------------- MFMA GEMM: H(bf16) = X @ W, tile 64x128x128 ----------------
template <bool BF16IN, bool ATT8, bool ATTIN>
__global__ __launch_bounds__(256) void mfma_gemm(const void* __restrict__ Xv,
                                                 const ushort* __restrict__ Wt,
                                                 ushort* __restrict__ H,
                                                 const float* __restrict__ attS,
                                                 const float* __restrict__ attD,
                                                 float* __restrict__ aS,
                                                 float* __restrict__ aD,
                                                 int nrows) {
    __shared__ __align__(16) char smem[16384 + 32768];
    ushort* lx = (ushort*)smem;            // 64 x 128 bf16 (swizzled)
    ushort* lw = (ushort*)(smem + 16384);  // 128 x 128 bf16 (swizzled)
    float*  hs = (float*)smem;             // ATT8 epilogue alias: 64 x 130 f32

    const int t = threadIdx.x;
    const int r0 = blockIdx.x * 64;

    // stage W
    {
        const int n = t >> 1, half = t & 1;
        const ushort* src = Wt + (size_t)n * 128 + half * 64;
        #pragma unroll
        for (int c = 0; c < 8; ++c) {
            int cx = half * 8 + c;
            uint4 v = *(const uint4*)(src + c * 8);
            *(uint4*)&lw[(n * 16 + (cx ^ (n & 7))) * 8] = v;
        }
    }
    // stage X
    {
        const int r = t >> 2, q = t & 3;
        const int grow = r0 + r;
        const uint4 z = {0, 0, 0, 0};
        #pragma unroll
        for (int cc = 0; cc < 4; ++cc) {
            int cx = q * 4 + cc;
            uint4 packed = z;
            if (grow < nrows) {
                if (BF16IN) {
                    packed = *(const uint4*)((const ushort*)Xv + (size_t)grow * 128 + cx * 8);
                } else {
                    const float* X = (const float*)Xv;
                    const float4 f0 = *(const float4*)(X + (size_t)grow * 128 + cx * 8);
                    const float4 f1 = *(const float4*)(X + (size_t)grow * 128 + cx * 8 + 4);
                    packed.x = (uint)f2bf(f0.x) | ((uint)f2bf(f0.y) << 16);
                    packed.y = (uint)f2bf(f0.z) | ((uint)f2bf(f0.w) << 16);
                    packed.z = (uint)f2bf(f1.x) | ((uint)f2bf(f1.y) << 16);
                    packed.w = (uint)f2bf(f1.z) | ((uint)f2bf(f1.w) << 16);
                }
            }
            *(uint4*)&lx[(r * 16 + (cx ^ (r & 7))) * 8] = packed;
        }
    }
    __syncthreads();

    const int wv = t >> 6, l = t & 63;
    const int row = wv * 16 + (l & 15);
    const int lg = l >> 4;
    f32x4 acc[8] = {};

    #pragma unroll
    for (int kb = 0; kb < 4; ++kb) {
        const int cx = kb * 4 + lg;
        bf16x8 a = *(const bf16x8*)&lx[(row * 16 + (cx ^ (row & 7))) * 8];
        #pragma unroll
        for (int nt = 0; nt < 8; ++nt) {
            const int n = nt * 16 + (l & 15);
            bf16x8 b = *(const bf16x8*)&lw[(n * 16 + (cx ^ (n & 7))) * 8];
            acc[nt] = __builtin_amdgcn_mfma_f32_16x16x32_bf16(a, b, acc[nt], 0, 0, 0);
        }
    }

    // C/D layout: col = lane&15, row = (lane>>4)*4 + reg
    #pragma unroll
    for (int reg = 0; reg < 4; ++reg) {
        const int grow = r0 + wv * 16 + lg * 4 + reg;
        if (grow < nrows) {
            #pragma unroll
            for (int nt = 0; nt < 8; ++nt)
                H[(size_t)grow * 128 + nt * 16 + (l & 15)] = f2bf(acc[nt][reg]);
        }
    }

    if (ATT8) {
        __syncthreads();   // all MFMA LDS reads done; safe to overwrite as hs
        #pragma unroll
        for (int reg = 0; reg < 4; ++reg) {
            const int r = wv * 16 + lg * 4 + reg;
            #pragma unroll
            for (int nt = 0; nt < 8; ++nt)
                hs[r * 130 + nt * 16 + (l & 15)] = acc[nt][reg];
        }
        __syncthreads();
        for (int q = t; q < 512; q += 256) {
            const int r = q >> 3, h = q & 7;
            if (r0 + r < nrows) {
                float sv = 0.f, dv = 0.f;
                #pragma unroll
                for (int j = 0; j < 16; ++j) {
                    const float hv = hs[r * 130 + h * 16 + j];
                    sv += hv * attS[h * 16 + j];
                    dv += hv * attD[h * 16 + j];
                }
                aS[(size_t)(r0 + r) * 8 + h] = sv;
                aD[(size_t)(r0 + r) * 8 + h] = dv;
            }
        }
    }

    if (ATTIN) {
        // lx still holds staged input rows. attS/attD = vs/vd; aS/aD = aS2/aD2.
        const int r = t >> 2, qq = t & 3;
        float ps = 0.f, pd = 0.f;
        #pragma unroll
        for (int cc = 0; cc < 4; ++cc) {
            const int cx = qq * 4 + cc;
            const uint4 p = *(const uint4*)&lx[(r * 16 + (cx ^ (r & 7))) * 8];
            const uint w[4] = {p.x, p.y, p.z, p.w};
            #pragma unroll
            for (int q = 0; q < 4; ++q) {
                const float e0 = bf2f(w[q] & 0xffffu);
                const float e1 = bf2f(w[q] >> 16);
                ps += e0 * attS[cx * 8 + 2 * q] + e1 * attS[cx * 8 + 2 * q + 1];
                pd += e0 * attD[cx * 8 + 2 * q] + e1 * attD[cx * 8 + 2 * q + 1];
            }
        }
        ps += __shfl_xor(ps, 1); ps += __shfl_xor(ps, 2);
        pd += __shfl_xor(pd, 1); pd += __shfl_xor(pd, 2);
        if (qq == 0 && r0 + r < nrows) { aS[r0 + r] = ps; aD[r0 + r] = pd; }
    }
}

// ---------------- agg layer 1: wave per dst, 4-slot load ring ----------------
// lane = 16g+i: group g handles edges j = 4t+g, lane covers channels [8i, 8i+8)
#define GISSUE(P, JJ)                                                          \
    {                                                                          \
        const int jx_ = (JJ);                                                  \
        const int sx_ = __shfl(s_l, jx_ & 63);                                 \
        P = zero4;                                                             \
        if (jx_ < rem) P = *(const uint4*)(Hm + (size_t)sx_ * 128 + i * 8);    \
    }

__global__ __launch_bounds__(256) void agg8(const int* __restrict__ rowptr,
                                            const ushort* __restrict__ csrc,
                                            const float* __restrict__ aS,
                                            const float* __restrict__ aD,
                                            const ushort* __restrict__ Hm,
                                            const float* __restrict__ bias,
                                            ushort* __restrict__ o1bf) {
    __shared__ float wlds[4][512];
    const int wv = threadIdx.x >> 6;
    const int d = blockIdx.x * 4 + wv;
    const int lane = threadIdx.x & 63;
    const int g = lane >> 4, i = lane & 15, hc = i >> 1;
    const int hw = lane & 7;
    const float adh = aD[(size_t)d * 8 + hw];

    const int base = rowptr[d], end = rowptr[d + 1];
    f32x2 acc[4] = {{0.f, 0.f}, {0.f, 0.f}, {0.f, 0.f}, {0.f, 0.f}};
    float ws = 0.f;
    const uint4 zero4 = {0, 0, 0, 0};

    for (int c0 = base; c0 < end; c0 += 64) {
        const int rem = min(64, end - c0);
        const int s_l = (lane < rem) ? (int)csrc[c0 + lane] : 0;

        // prime the ring FIRST so gather latency hides under the exp phase
        uint4 p0, p1, p2, p3;
        GISSUE(p0, g); GISSUE(p1, g + 4); GISSUE(p2, g + 8); GISSUE(p3, g + 12);

        // weight table: wlds[wv][j*8+h], 8 edges x 8 heads per pass
        const int nwc = (rem + 7) >> 3;
        for (int jj = 0; jj < nwc; ++jj) {
            const int j = jj * 8 + (lane >> 3);
            const int sj = __shfl(s_l, j & 63);
            float w = 0.f;
            if (j < rem) w = __expf(lrelu(aS[(size_t)sj * 8 + hw] + adh));
            wlds[wv][j * 8 + hw] = w;
        }
        // wave-private LDS, lockstep within wave => no barrier

        const int niter = (rem + 3) >> 2;
        for (int tb = 0; tb < niter; tb += 4) {
            const int j0 = 4 * tb + g;
            {
                const float w = (j0 < rem) ? wlds[wv][j0 * 8 + hc] : 0.f;
                fma8v(acc, p0, w, ws);
                GISSUE(p0, j0 + 16);
            }
            {
                const int j1 = j0 + 4;
                const float w = (j1 < rem) ? wlds[wv][j1 * 8 + hc] : 0.f;
                fma8v(acc, p1, w, ws);
                GISSUE(p1, j1 + 16);
            }
            {
                const int j2 = j0 + 8;
                const float w = (j2 < rem) ? wlds[wv][j2 * 8 + hc] : 0.f;
                fma8v(acc, p2, w, ws);
                GISSUE(p2, j2 + 16);
            }
            {
                const int j3 = j0 + 12;
                const float w = (j3 < rem) ? wlds[wv][j3 * 8 + hc] : 0.f;
                fma8v(acc, p3, w, ws);
                GISSUE(p3, j3 + 16);
            }
        }
    }

    #pragma unroll
    for (int k = 0; k < 4; ++k) {
        acc[k].x += __shfl_xor(acc[k].x, 16); acc[k].x += __shfl_xor(acc[k].x, 32);
        acc[k].y += __shfl_xor(acc[k].y, 16); acc[k].y += __shfl_xor(acc[k].y, 32);
    }
    ws += __shfl_xor(ws, 16);
    ws += __shfl_xor(ws, 32);

    if (g == 0) {
        const float inv = 1.f / (ws + EPS);
        float v[8];
        #pragma unroll
        for (int k = 0; k < 4; ++k) {
            v[2 * k]     = fmaxf(acc[k].x * inv + bias[i * 8 + 2 * k], 0.f);
            v[2 * k + 1] = fmaxf(acc[k].y * inv + bias[i * 8 + 2 * k + 1], 0.f);
        }
        uint4 pk;
        pk.x = (uint)f2bf(v[0]) | ((uint)f2bf(v[1]) << 16);
        pk.y = (uint)f2bf(v[2]) | ((uint)f2bf(v[3]) << 16);
        pk.z = (uint)f2bf(v[4]) | ((uint)f2bf(v[5]) << 16);
        pk.w = (uint)f2bf(v[6]) | ((uint)f2bf(v[7]) << 16);
        *(uint4*)(o1bf + (size_t)d * 128 + i * 8) = pk;
    }
}

// ---------------- agg layer 2: single head, 4-slot load ring ----------------
__global__ __launch_bounds__(256) void agg1(const int* __restrict__ rowptr,
                                            const ushort* __restrict__ csrc,
                                            const float* __restrict__ aS,
                                            const float* __restrict__ aD,
                                            const ushort* __restrict__ Hm,
                                            const float* __restrict__ bias,
                                            float* __restrict__ out) {
    __shared__ float wlds[4][64];
    const int wv = threadIdx.x >> 6;
    const int d = blockIdx.x * 4 + wv;
    const int lane = threadIdx.x & 63;
    const int g = lane >> 4, i = lane & 15;
    const float ad = aD[d];

    const int base = rowptr[d], end = rowptr[d + 1];
    f32x2 acc[4] = {{0.f, 0.f}, {0.f, 0.f}, {0.f, 0.f}, {0.f, 0.f}};
    float ws = 0.f;
    const uint4 zero4 = {0, 0, 0, 0};

    for (int c0 = base; c0 < end; c0 += 64) {
        const int rem = min(64, end - c0);
        const int s_l = (lane < rem) ? (int)csrc[c0 + lane] : 0;

        uint4 p0, p1, p2, p3;
        GISSUE(p0, g); GISSUE(p1, g + 4); GISSUE(p2, g + 8); GISSUE(p3, g + 12);

        wlds[wv][lane] = (lane < rem) ? __expf(lrelu(aS[s_l] + ad)) : 0.f;

        const int niter = (rem + 3) >> 2;
        for (int tb = 0; tb < niter; tb += 4) {
            const int j0 = 4 * tb + g;
            {
                const float w = (j0 < rem) ? wlds[wv][j0] : 0.f;
                fma8v(acc, p0, w, ws);
                GISSUE(p0, j0 + 16);
            }
            {
                const int j1 = j0 + 4;
                const float w = (j1 < rem) ? wlds[wv][j1] : 0.f;
                fma8v(acc, p1, w, ws);
                GISSUE(p1, j1 + 16);
            }
            {
                const int j2 = j0 + 8;
                const float w = (j2 < rem) ? wlds[wv][j2] : 0.f;
                fma8v(acc, p2, w, ws);
                GISSUE(p2, j2 + 16);
            }
            {
                const int j3 = j0 + 12;
                const float w = (j3 < rem) ? wlds[wv][j3] : 0.f;
                fma8v(acc, p3, w, ws);
                GISSUE(p3, j3 + 16);
            }
        }
    }

    #pragma unroll
    for (int k = 0; k < 4; ++k) {
        acc[k].x += __shfl_xor(acc[k].x, 16); acc[k].x += __shfl_xor(acc[k].x, 32);
        acc[k].y += __shfl_xor(acc[k].y, 16); acc[k].y += __shfl_xor(acc[k].y, 32);
    }
    ws += __shfl_xor(ws, 16);
    ws += __shfl_xor(ws, 32);

    if (g == 0) {
        const float inv = 1.f / (ws + EPS);
        float4 o0, o1v;
        o0.x = acc[0].x * inv + bias[i * 8 + 0];
        o0.y = acc[0].y * inv + bias[i * 8 + 1];
        o0.z = acc[1].x * inv + bias[i * 8 + 2];
        o0.w = acc[1].y * inv + bias[i * 8 + 3];
        o1v.x = acc[2].x * inv + bias[i * 8 + 4];
        o1v.y = acc[2].y * inv + bias[i * 8 + 5];
        o1v.z = acc[3].x * inv + bias[i * 8 + 6];
        o1v.w = acc[3].y * inv + bias[i * 8 + 7];
        *(float4*)(out + (size_t)d * 128 + i * 8) = o0;
        *(float4*)(out + (size_t)d * 128 + i * 8 + 4) = o1v;
    }
}

extern "C" void kernel_launch(void* const* d_in, const int* in_sizes, int n_in,
                              void* d_out, int out_size, void* d_ws, size_t ws_size,
                              hipStream_t stream) {
    const float* x        = (const float*)d_in[0];
    const int*   ei       = (const int*)  d_in[1];
    const float* W1       = (const float*)d_in[2];
    const float* att_src1 = (const float*)d_in[3];
    const float* att_dst1 = (const float*)d_in[4];
    const float* b1       = (const float*)d_in[5];
    const float* W2       = (const float*)d_in[6];
    const float* att_src2 = (const float*)d_in[7];
    const float* att_dst2 = (const float*)d_in[8];
    const float* b2       = (const float*)d_in[9];
    float* out = (float*)d_out;

    // Workspace layout
    ushort* Hbf  = (ushort*)d_ws;                          // N*128 bf16 (h1, then h2)
    ushort* o1bf = Hbf + (size_t)N_NODES * 128;            // N*128 bf16
    float*  aS1  = (float*)(o1bf + (size_t)N_NODES * 128); // N*8
    float*  aD1  = aS1 + (size_t)N_NODES * 8;              // N*8
    float*  aS2  = aD1 + (size_t)N_NODES * 8;              // N
    float*  aD2  = aS2 + N_NODES;                          // N
    float*  vs   = aD2 + N_NODES;                          // 128
    float*  vd   = vs + 128;                               // 128
    ushort* W1t  = (ushort*)(vd + 128);                    // 128*128
    ushort* W2t  = W1t + 128 * 128;                        // 128*128
    uint* cnt16  = (uint*)(W2t + 128 * 128);               // (N+1)/2 words
    int* rowptr  = (int*)(cnt16 + (N_NODES + 1) / 2 + 1);  // N+1
    int* bsum    = rowptr + N_NODES + 1;                   // 128
    ushort* rank = (ushort*)(bsum + 128);                  // ETOT
    ushort* csrc = rank + ETOT + 2;                        // ETOT (ushort)

    const int zblk = ((N_NODES + 1) / 2 + 255) / 256;      // 98
    const int eblk = (ETOT + 255) / 256;                   // 3321
    const int gemm_blocks = (N_NODES + 63) / 64;           // 782
    const int agg_blocks = N_NODES / 4;                    // 12500

    convert_W<<<2 + zblk, 256, 0, stream>>>(W1, W2, att_src2, att_dst2,
                                            W1t, W2t, vs, vd, cnt16);
    count_rank<<<eblk, 256, 0, stream>>>(ei, cnt16, rank);
    block_sums<<<NBLK_SCAN, SCAN_BLK, 0, stream>>>(cnt16, bsum);
    scan_final_fused<<<NBLK_SCAN, SCAN_BLK, 0, stream>>>(cnt16, bsum, rowptr);
    scatter_kernel<<<eblk, 256, 0, stream>>>(ei, rowptr, rank, csrc);

    // Layer 1
    mfma_gemm<false, true, false><<<gemm_blocks, 256, 0, stream>>>(
        x, W1t, Hbf, att_src1, att_dst1, aS1, aD1, N_NODES);
    agg8<<<agg_blocks, 256, 0, stream>>>(rowptr, csrc, aS1, aD1, Hbf, b1, o1bf);

    // Layer 2 (GEMM2 also computes a2 dots from its staged input rows)
    mfma_gemm<true, false, true><<<gemm_blocks, 256, 0, stream>>>(
        o1bf, W2t, Hbf, vs, vd, aS2, aD2, N_NODES);
    agg1<<<agg_blocks, 256, 0, stream>>>(rowptr, csrc, aS2, aD2, Hbf, b2, out);
}

// Round 11
// 198.676 us; speedup vs baseline: 1.4499x; 1.0943x over previous
//
#include <hip/hip_runtime.h>

// GraphGATNet 2-layer GAT. Round 11:
//  - REVERT R10 packed-FMA agg (VGPR 28->44 cut occupancy 67->44%, 48->57us;
//    same lesson as R8's 6-slot ring: agg is miss-latency bound, occupancy
//    (wave count) is the currency, not per-edge VALU).
//  - agg = exact R5 structure (proven 48us: scalar acc[8], 2-deep prefetch per
//    16-lane group, LDS weight table) + PERSISTENT grid-stride waves (2048
//    blocks; each wave ~6 dsts) to remove block-retire tail imbalance.
//  - csrc ushort kept from R10 (halves scatter writes + agg index reads).
//  - cnt 32-bit unpacked (halves atomic contention vs 2-nodes-per-word).
//  - CSR rank-trick, scan_final_fused, ATT8/ATTIN fusions unchanged.

constexpr int N_NODES = 50000;
constexpr int E_EDGES = 800000;
constexpr int ETOT = E_EDGES + N_NODES;
constexpr float NEG_SLOPE = 0.2f;
constexpr float EPS = 1e-16f;
constexpr int SCAN_BLK = 512;
constexpr int NBLK_SCAN = (N_NODES + SCAN_BLK - 1) / SCAN_BLK;   // 98

typedef short bf16x8 __attribute__((ext_vector_type(8)));
typedef float f32x4 __attribute__((ext_vector_type(4)));

__device__ __forceinline__ float lrelu(float x) { return x > 0.f ? x : NEG_SLOPE * x; }
__device__ __forceinline__ ushort f2bf(float f) {
    uint u = __float_as_uint(f);
    return (ushort)((u + 0x7fffu + ((u >> 16) & 1u)) >> 16);
}
__device__ __forceinline__ float bf2f(uint u) { return __uint_as_float(u << 16); }

__device__ __forceinline__ void fma8(float* acc, uint4 p, float w, float& ws) {
    ws += w;
    acc[0] += w * bf2f(p.x & 0xffffu); acc[1] += w * bf2f(p.x >> 16);
    acc[2] += w * bf2f(p.y & 0xffffu); acc[3] += w * bf2f(p.y >> 16);
    acc[4] += w * bf2f(p.z & 0xffffu); acc[5] += w * bf2f(p.z >> 16);
    acc[6] += w * bf2f(p.w & 0xffffu); acc[7] += w * bf2f(p.w >> 16);
}

// ---------------- setup: W->bf16T, vs/vd = W2@att2, zero cnt ----------------
__global__ __launch_bounds__(256) void convert_W(const float* __restrict__ W1,
                                                 const float* __restrict__ W2,
                                                 const float* __restrict__ attS2,
                                                 const float* __restrict__ attD2,
                                                 ushort* __restrict__ W1t,
                                                 ushort* __restrict__ W2t,
                                                 float* __restrict__ vs,
                                                 float* __restrict__ vd,
                                                 uint* __restrict__ cnt) {
    const int t = threadIdx.x;
    if (blockIdx.x >= 2) {
        const int i = (blockIdx.x - 2) * 256 + t;
        if (i < N_NODES) cnt[i] = 0;
        return;
    }
    const float* W = (blockIdx.x == 0) ? W1 : W2;
    ushort* Wt = (blockIdx.x == 0) ? W1t : W2t;
    const int n = t >> 1, k0 = (t & 1) * 64;
    for (int k = 0; k < 64; k += 2) {
        uint lo = f2bf(W[(size_t)(k0 + k) * 128 + n]);
        uint hi = f2bf(W[(size_t)(k0 + k + 1) * 128 + n]);
        *(uint*)&Wt[(size_t)n * 128 + k0 + k] = lo | (hi << 16);
    }
    if (blockIdx.x == 1) {
        const int k = t & 127;
        const float* av = (t < 128) ? attS2 : attD2;
        float* dst = (t < 128) ? vs : vd;
        float s = 0.f;
        for (int c = 0; c < 128; ++c) s += W2[(size_t)k * 128 + c] * av[c];
        dst[k] = s;
    }
}

// count + rank in one pass (32-bit counts)
__global__ __launch_bounds__(256) void count_rank(const int* __restrict__ ei,
                                                  uint* __restrict__ cnt,
                                                  ushort* __restrict__ rank) {
    int e = blockIdx.x * blockDim.x + threadIdx.x;
    if (e >= ETOT) return;
    int d = (e < E_EDGES) ? ei[E_EDGES + e] : (e - E_EDGES);
    uint old = atomicAdd(&cnt[d], 1u);
    rank[e] = (ushort)old;
}

__global__ __launch_bounds__(SCAN_BLK) void block_sums(const uint* __restrict__ cnt,
                                                       int* __restrict__ bsum) {
    __shared__ int sm[SCAN_BLK];
    int i = blockIdx.x * SCAN_BLK + threadIdx.x;
    sm[threadIdx.x] = (i < N_NODES) ? (int)cnt[i] : 0;
    __syncthreads();
    for (int off = SCAN_BLK / 2; off > 0; off >>= 1) {
        if (threadIdx.x < off) sm[threadIdx.x] += sm[threadIdx.x + off];
        __syncthreads();
    }
    if (threadIdx.x == 0) bsum[blockIdx.x] = sm[0];
}

__global__ __launch_bounds__(SCAN_BLK) void scan_final_fused(const uint* __restrict__ cnt,
                                                             const int* __restrict__ bsum,
                                                             int* __restrict__ rowptr) {
    __shared__ int sb[128];
    __shared__ int sm[SCAN_BLK];
    const int t = threadIdx.x;
    if (t < 128) sb[t] = (t < NBLK_SCAN) ? bsum[t] : 0;
    __syncthreads();
    for (int off = 1; off < 128; off <<= 1) {
        int v = 0;
        if (t < 128 && t >= off) v = sb[t - off];
        __syncthreads();
        if (t < 128) sb[t] += v;
        __syncthreads();
    }
    const int bid = blockIdx.x;
    const int bpre = sb[bid] - bsum[bid];

    const int i = bid * SCAN_BLK + t;
    const int v = (i < N_NODES) ? (int)cnt[i] : 0;
    sm[t] = v;
    __syncthreads();
    for (int off = 1; off < SCAN_BLK; off <<= 1) {
        int x = (t >= off) ? sm[t - off] : 0;
        __syncthreads();
        sm[t] += x;
        __syncthreads();
    }
    if (i < N_NODES) rowptr[i] = bpre + sm[t] - v;
    if (bid == 0 && t == 0) rowptr[N_NODES] = ETOT;
}

__global__ __launch_bounds__(256) void scatter_kernel(const int* __restrict__ ei,
                                                      const int* __restrict__ rowptr,
                                                      const ushort* __restrict__ rank,
                                                      ushort* __restrict__ csrc) {
    int e = blockIdx.x * blockDim.x + threadIdx.x;
    if (e >= ETOT) return;
    int s, d;
    if (e < E_EDGES) { s = ei[e]; d = ei[E_EDGES + e]; }
    else             { s = d = e - E_EDGES; }
    const int pos = rowptr[d] + (int)rank[e];
    __builtin_nontemporal_store((ushort)s, &csrc[pos]);
}

// ---------------- MFMA GEMM: H(bf16) = X @ W, tile 64x128x128 ----------------
template <bool BF16IN, bool ATT8, bool ATTIN>
__global__ __launch_bounds__(256) void mfma_gemm(const void* __restrict__ Xv,
                                                 const ushort* __restrict__ Wt,
                                                 ushort* __restrict__ H,
                                                 const float* __restrict__ attS,
                                                 const float* __restrict__ attD,
                                                 float* __restrict__ aS,
                                                 float* __restrict__ aD,
                                                 int nrows) {
    __shared__ __align__(16) char smem[16384 + 32768];
    ushort* lx = (ushort*)smem;            // 64 x 128 bf16 (swizzled)
    ushort* lw = (ushort*)(smem + 16384);  // 128 x 128 bf16 (swizzled)
    float*  hs = (float*)smem;             // ATT8 epilogue alias: 64 x 130 f32

    const int t = threadIdx.x;
    const int r0 = blockIdx.x * 64;

    // stage W
    {
        const int n = t >> 1, half = t & 1;
        const ushort* src = Wt + (size_t)n * 128 + half * 64;
        #pragma unroll
        for (int c = 0; c < 8; ++c) {
            int cx = half * 8 + c;
            uint4 v = *(const uint4*)(src + c * 8);
            *(uint4*)&lw[(n * 16 + (cx ^ (n & 7))) * 8] = v;
        }
    }
    // stage X
    {
        const int r = t >> 2, q = t & 3;
        const int grow = r0 + r;
        const uint4 z = {0, 0, 0, 0};
        #pragma unroll
        for (int cc = 0; cc < 4; ++cc) {
            int cx = q * 4 + cc;
            uint4 packed = z;
            if (grow < nrows) {
                if (BF16IN) {
                    packed = *(const uint4*)((const ushort*)Xv + (size_t)grow * 128 + cx * 8);
                } else {
                    const float* X = (const float*)Xv;
                    const float4 f0 = *(const float4*)(X + (size_t)grow * 128 + cx * 8);
                    const float4 f1 = *(const float4*)(X + (size_t)grow * 128 + cx * 8 + 4);
                    packed.x = (uint)f2bf(f0.x) | ((uint)f2bf(f0.y) << 16);
                    packed.y = (uint)f2bf(f0.z) | ((uint)f2bf(f0.w) << 16);
                    packed.z = (uint)f2bf(f1.x) | ((uint)f2bf(f1.y) << 16);
                    packed.w = (uint)f2bf(f1.z) | ((uint)f2bf(f1.w) << 16);
                }
            }
            *(uint4*)&lx[(r * 16 + (cx ^ (r & 7))) * 8] = packed;
        }
    }
    __syncthreads();

    const int wv = t >> 6, l = t & 63;
    const int row = wv * 16 + (l & 15);
    const int lg = l >> 4;
    f32x4 acc[8] = {};

    #pragma unroll
    for (int kb = 0; kb < 4; ++kb) {
        const int cx = kb * 4 + lg;
        bf16x8 a = *(const bf16x8*)&lx[(row * 16 + (cx ^ (row & 7))) * 8];
        #pragma unroll
        for (int nt = 0; nt < 8; ++nt) {
            const int n = nt * 16 + (l & 15);
            bf16x8 b = *(const bf16x8*)&lw[(n * 16 + (cx ^ (n & 7))) * 8];
            acc[nt] = __builtin_amdgcn_mfma_f32_16x16x32_bf16(a, b, acc[nt], 0, 0, 0);
        }
    }

    // C/D layout: col = lane&15, row = (lane>>4)*4 + reg
    #pragma unroll
    for (int reg = 0; reg < 4; ++reg) {
        const int grow = r0 + wv * 16 + lg * 4 + reg;
        if (grow < nrows) {
            #pragma unroll
            for (int nt = 0; nt < 8; ++nt)
                H[(size_t)grow * 128 + nt * 16 + (l & 15)] = f2bf(acc[nt][reg]);
        }
    }

    if (ATT8) {
        __syncthreads();   // all MFMA LDS reads done; safe to overwrite as hs
        #pragma unroll
        for (int reg = 0; reg < 4; ++reg) {
            const int r = wv * 16 + lg * 4 + reg;
            #pragma unroll
            for (int nt = 0; nt < 8; ++nt)
                hs[r * 130 + nt * 16 + (l & 15)] = acc[nt][reg];
        }
        __syncthreads();
        for (int q = t; q < 512; q += 256) {
            const int r = q >> 3, h = q & 7;
            if (r0 + r < nrows) {
                float sv = 0.f, dv = 0.f;
                #pragma unroll
                for (int j = 0; j < 16; ++j) {
                    const float hv = hs[r * 130 + h * 16 + j];
                    sv += hv * attS[h * 16 + j];
                    dv += hv * attD[h * 16 + j];
                }
                aS[(size_t)(r0 + r) * 8 + h] = sv;
                aD[(size_t)(r0 + r) * 8 + h] = dv;
            }
        }
    }

    if (ATTIN) {
        // lx still holds staged input rows. attS/attD = vs/vd; aS/aD = aS2/aD2.
        const int r = t >> 2, qq = t & 3;
        float ps = 0.f, pd = 0.f;
        #pragma unroll
        for (int cc = 0; cc < 4; ++cc) {
            const int cx = qq * 4 + cc;
            const uint4 p = *(const uint4*)&lx[(r * 16 + (cx ^ (r & 7))) * 8];
            const uint w[4] = {p.x, p.y, p.z, p.w};
            #pragma unroll
            for (int q = 0; q < 4; ++q) {
                const float e0 = bf2f(w[q] & 0xffffu);
                const float e1 = bf2f(w[q] >> 16);
                ps += e0 * attS[cx * 8 + 2 * q] + e1 * attS[cx * 8 + 2 * q + 1];
                pd += e0 * attD[cx * 8 + 2 * q] + e1 * attD[cx * 8 + 2 * q + 1];
            }
        }
        ps += __shfl_xor(ps, 1); ps += __shfl_xor(ps, 2);
        pd += __shfl_xor(pd, 1); pd += __shfl_xor(pd, 2);
        if (qq == 0 && r0 + r < nrows) { aS[r0 + r] = ps; aD[r0 + r] = pd; }
    }
}

// ---------------- agg layer 1: persistent waves, R5 inner loop ----------------
// lane = 16g+i: group g handles edges j = 4t+g, lane covers channels [8i, 8i+8)
__global__ __launch_bounds__(256) void agg8(const int* __restrict__ rowptr,
                                            const ushort* __restrict__ csrc,
                                            const float* __restrict__ aS,
                                            const float* __restrict__ aD,
                                            const ushort* __restrict__ Hm,
                                            const float* __restrict__ bias,
                                            ushort* __restrict__ o1bf) {
    __shared__ float wlds[4][512];
    const int wv = threadIdx.x >> 6;
    const int lane = threadIdx.x & 63;
    const int g = lane >> 4, i = lane & 15, hc = i >> 1;
    const int hw = lane & 7;
    const int wid = blockIdx.x * 4 + wv;
    const int nw = gridDim.x * 4;
    const uint4 zero4 = {0, 0, 0, 0};

    for (int d = wid; d < N_NODES; d += nw) {
        const float adh = aD[(size_t)d * 8 + hw];
        const int base = rowptr[d], end = rowptr[d + 1];
        float acc[8] = {0.f, 0.f, 0.f, 0.f, 0.f, 0.f, 0.f, 0.f};
        float ws = 0.f;

        for (int c0 = base; c0 < end; c0 += 64) {
            const int rem = min(64, end - c0);
            const int s_l = (lane < rem) ? (int)csrc[c0 + lane] : 0;

            // weight table: wlds[wv][j*8+h], 8 edges x 8 heads per pass
            const int nwc = (rem + 7) >> 3;
            for (int jj = 0; jj < nwc; ++jj) {
                const int j = jj * 8 + (lane >> 3);
                const int sj = __shfl(s_l, j & 63);
                float w = 0.f;
                if (j < rem) w = __expf(lrelu(aS[(size_t)sj * 8 + hw] + adh));
                wlds[wv][j * 8 + hw] = w;
            }
            // wave-private LDS, lockstep within wave => no barrier

            // gather: 4 edges per iteration (one per group), 1-deep prefetch
            const int niter = (rem + 3) >> 2;
            int j = g;
            int scur = __shfl(s_l, j);
            uint4 pcur = zero4;
            if (j < rem) pcur = *(const uint4*)(Hm + (size_t)scur * 128 + i * 8);
            for (int tt = 0; tt < niter; ++tt) {
                const int jn = j + 4;
                const int snxt = __shfl(s_l, jn & 63);
                uint4 pnxt = zero4;
                if (jn < rem) pnxt = *(const uint4*)(Hm + (size_t)snxt * 128 + i * 8);
                float w = 0.f;
                if (j < rem) w = wlds[wv][j * 8 + hc];
                fma8(acc, pcur, w, ws);
                pcur = pnxt;
                j = jn;
            }
        }

        #pragma unroll
        for (int k = 0; k < 8; ++k) {
            acc[k] += __shfl_xor(acc[k], 16);
            acc[k] += __shfl_xor(acc[k], 32);
        }
        ws += __shfl_xor(ws, 16);
        ws += __shfl_xor(ws, 32);

        if (g == 0) {
            const float inv = 1.f / (ws + EPS);
            float v[8];
            #pragma unroll
            for (int k = 0; k < 8; ++k) v[k] = fmaxf(acc[k] * inv + bias[i * 8 + k], 0.f);
            uint4 pk;
            pk.x = (uint)f2bf(v[0]) | ((uint)f2bf(v[1]) << 16);
            pk.y = (uint)f2bf(v[2]) | ((uint)f2bf(v[3]) << 16);
            pk.z = (uint)f2bf(v[4]) | ((uint)f2bf(v[5]) << 16);
            pk.w = (uint)f2bf(v[6]) | ((uint)f2bf(v[7]) << 16);
            *(uint4*)(o1bf + (size_t)d * 128 + i * 8) = pk;
        }
    }
}

// ---------------- agg layer 2: persistent waves, single head ----------------
__global__ __launch_bounds__(256) void agg1(const int* __restrict__ rowptr,
                                            const ushort* __restrict__ csrc,
                                            const float* __restrict__ aS,
                                            const float* __restrict__ aD,
                                            const ushort* __restrict__ Hm,
                                            const float* __restrict__ bias,
                                            float* __restrict__ out) {
    const int wv = threadIdx.x >> 6;
    const int lane = threadIdx.x & 63;
    const int g = lane >> 4, i = lane & 15;
    const int wid = blockIdx.x * 4 + wv;
    const int nw = gridDim.x * 4;
    const uint4 zero4 = {0, 0, 0, 0};

    for (int d = wid; d < N_NODES; d += nw) {
        const float ad = aD[d];
        const int base = rowptr[d], end = rowptr[d + 1];
        float acc[8] = {0.f, 0.f, 0.f, 0.f, 0.f, 0.f, 0.f, 0.f};
        float ws = 0.f;

        for (int c0 = base; c0 < end; c0 += 64) {
            const int rem = min(64, end - c0);
            const int s_l = (lane < rem) ? (int)csrc[c0 + lane] : 0;
            const float w_l = (lane < rem) ? __expf(lrelu(aS[s_l] + ad)) : 0.f;

            const int niter = (rem + 3) >> 2;
            int j = g;
            int scur = __shfl(s_l, j);
            float wcur = __shfl(w_l, j);
            uint4 pcur = zero4;
            if (j < rem) pcur = *(const uint4*)(Hm + (size_t)scur * 128 + i * 8);
            for (int tt = 0; tt < niter; ++tt) {
                const int jn = j + 4;
                const int snxt = __shfl(s_l, jn & 63);
                const float wnxt = __shfl(w_l, jn & 63);
                uint4 pnxt = zero4;
                if (jn < rem) pnxt = *(const uint4*)(Hm + (size_t)snxt * 128 + i * 8);
                float w = (j < rem) ? wcur : 0.f;
                fma8(acc, pcur, w, ws);
                pcur = pnxt;
                wcur = wnxt;
                j = jn;
            }
        }

        #pragma unroll
        for (int k = 0; k < 8; ++k) {
            acc[k] += __shfl_xor(acc[k], 16);
            acc[k] += __shfl_xor(acc[k], 32);
        }
        ws += __shfl_xor(ws, 16);
        ws += __shfl_xor(ws, 32);

        if (g == 0) {
            const float inv = 1.f / (ws + EPS);
            float4 o0, o1v;
            o0.x = acc[0] * inv + bias[i * 8 + 0];
            o0.y = acc[1] * inv + bias[i * 8 + 1];
            o0.z = acc[2] * inv + bias[i * 8 + 2];
            o0.w = acc[3] * inv + bias[i * 8 + 3];
            o1v.x = acc[4] * inv + bias[i * 8 + 4];
            o1v.y = acc[5] * inv + bias[i * 8 + 5];
            o1v.z = acc[6] * inv + bias[i * 8 + 6];
            o1v.w = acc[7] * inv + bias[i * 8 + 7];
            *(float4*)(out + (size_t)d * 128 + i * 8) = o0;
            *(float4*)(out + (size_t)d * 128 + i * 8 + 4) = o1v;
        }
    }
}

extern "C" void kernel_launch(void* const* d_in, const int* in_sizes, int n_in,
                              void* d_out, int out_size, void* d_ws, size_t ws_size,
                              hipStream_t stream) {
    const float* x        = (const float*)d_in[0];
    const int*   ei       = (const int*)  d_in[1];
    const float* W1       = (const float*)d_in[2];
    const float* att_src1 = (const float*)d_in[3];
    const float* att_dst1 = (const float*)d_in[4];
    const float* b1       = (const float*)d_in[5];
    const float* W2       = (const float*)d_in[6];
    const float* att_src2 = (const float*)d_in[7];
    const float* att_dst2 = (const float*)d_in[8];
    const float* b2       = (const float*)d_in[9];
    float* out = (float*)d_out;

    // Workspace layout
    ushort* Hbf  = (ushort*)d_ws;                          // N*128 bf16 (h1, then h2)
    ushort* o1bf = Hbf + (size_t)N_NODES * 128;            // N*128 bf16
    float*  aS1  = (float*)(o1bf + (size_t)N_NODES * 128); // N*8
    float*  aD1  = aS1 + (size_t)N_NODES * 8;              // N*8
    float*  aS2  = aD1 + (size_t)N_NODES * 8;              // N
    float*  aD2  = aS2 + N_NODES;                          // N
    float*  vs   = aD2 + N_NODES;                          // 128
    float*  vd   = vs + 128;                               // 128
    ushort* W1t  = (ushort*)(vd + 128);                    // 128*128
    ushort* W2t  = W1t + 128 * 128;                        // 128*128
    uint* cnt    = (uint*)(W2t + 128 * 128);               // N
    int* rowptr  = (int*)(cnt + N_NODES + 1);              // N+1
    int* bsum    = rowptr + N_NODES + 1;                   // 128
    ushort* rank = (ushort*)(bsum + 128);                  // ETOT
    ushort* csrc = rank + ETOT + 2;                        // ETOT (ushort)

    const int zblk = (N_NODES + 255) / 256;                // 196
    const int eblk = (ETOT + 255) / 256;                   // 3321
    const int gemm_blocks = (N_NODES + 63) / 64;           // 782
    const int agg_blocks = 2048;                           // persistent: 8192 waves

    convert_W<<<2 + zblk, 256, 0, stream>>>(W1, W2, att_src2, att_dst2,
                                            W1t, W2t, vs, vd, cnt);
    count_rank<<<eblk, 256, 0, stream>>>(ei, cnt, rank);
    block_sums<<<NBLK_SCAN, SCAN_BLK, 0, stream>>>(cnt, bsum);
    scan_final_fused<<<NBLK_SCAN, SCAN_BLK, 0, stream>>>(cnt, bsum, rowptr);
    scatter_kernel<<<eblk, 256, 0, stream>>>(ei, rowptr, rank, csrc);

    // Layer 1
    mfma_gemm<false, true, false><<<gemm_blocks, 256, 0, stream>>>(
        x, W1t, Hbf, att_src1, att_dst1, aS1, aD1, N_NODES);
    agg8<<<agg_blocks, 256, 0, stream>>>(rowptr, csrc, aS1, aD1, Hbf, b1, o1bf);

    // Layer 2 (GEMM2 also computes a2 dots from its staged input rows)
    mfma_gemm<true, false, true><<<gemm_blocks, 256, 0, stream>>>(
        o1bf, W2t, Hbf, vs, vd, aS2, aD2, N_NODES);
    agg1<<<agg_blocks, 256, 0, stream>>>(rowptr, csrc, aS2, aD2, Hbf, b2, out);
}